// Round 1
// baseline (279.128 us; speedup 1.0000x reference)
//
#include <hip/hip_runtime.h>
#include <math.h>

#define BB   64
#define NN   1024
#define FIN  16
#define DIM  64
#define KK   20
#define EPSV 1e-5f
#define SLOPE 0.2f
#define BN_COUNT (BB*NN)

__device__ inline float wred_sum(float v){
  #pragma unroll
  for (int m = 32; m > 0; m >>= 1) v += __shfl_xor(v, m, 64);
  return v;
}
__device__ inline float wred_max(float v){
  #pragma unroll
  for (int m = 32; m > 0; m >>= 1) v = fmaxf(v, __shfl_xor(v, m, 64));
  return v;
}

// ---------------- kA: norms + emb·att_em_i / emb·att_em_j ----------------
__global__ void kA(const float* __restrict__ emb,
                   const float* __restrict__ att_em_i,
                   const float* __restrict__ att_em_j,
                   float* __restrict__ nrm, float* __restrict__ e_i, float* __restrict__ e_j){
  int n = blockIdx.x, d = threadIdx.x;
  float v = emb[n*DIM + d];
  float ss = wred_sum(v*v);
  float di = wred_sum(v*att_em_i[d]);
  float dj = wred_sum(v*att_em_j[d]);
  if (d == 0){ nrm[n] = sqrtf(ss); e_i[n] = di; e_j[n] = dj; }
}

// ---------------- kB: per-row cosine + top-20 (lax.top_k semantics) ------
__global__ void kB(const float* __restrict__ emb, const float* __restrict__ nrm,
                   int* __restrict__ topk){
  __shared__ float cosv[NN];
  __shared__ __align__(16) float embi[DIM];
  __shared__ float bv[256];
  __shared__ int   bi[256];
  int i = blockIdx.x, t = threadIdx.x;
  if (t < DIM) embi[t] = emb[i*DIM + t];
  __syncthreads();
  float ni = nrm[i];
  int g = t >> 4, l16 = t & 15;
  const float4* e4 = (const float4*)emb;
  float4 a4 = ((const float4*)embi)[l16];
  for (int jb = 0; jb < NN; jb += 16){
    int j = jb + g;
    float4 b4 = e4[j*(DIM/4) + l16];
    float p = a4.x*b4.x + a4.y*b4.y + a4.z*b4.z + a4.w*b4.w;
    p += __shfl_xor(p, 1, 64); p += __shfl_xor(p, 2, 64);
    p += __shfl_xor(p, 4, 64); p += __shfl_xor(p, 8, 64);
    if (l16 == 0) cosv[j] = p / (ni * nrm[j]);
  }
  __syncthreads();
  for (int k = 0; k < KK; k++){
    float best = -1e30f; int bidx = NN;
    for (int j = t; j < NN; j += 256){
      float v = cosv[j];
      if (v > best){ best = v; bidx = j; }   // increasing j => first (lowest idx) wins ties
    }
    bv[t] = best; bi[t] = bidx;
    __syncthreads();
    for (int s = 128; s > 0; s >>= 1){
      if (t < s){
        float v2 = bv[t+s]; int i2 = bi[t+s];
        if (v2 > bv[t] || (v2 == bv[t] && i2 < bi[t])){ bv[t] = v2; bi[t] = i2; }
      }
      __syncthreads();
    }
    if (t == 0){ topk[i*KK + k] = bi[0]; cosv[bi[0]] = -1e30f; }
    __syncthreads();
  }
}

// ---------------- kC: h = data @ lin_w^T ; s_i, s_j ----------------------
__global__ void kC(const float* __restrict__ data, const float* __restrict__ lin_w,
                   const float* __restrict__ att_i, const float* __restrict__ att_j,
                   const float* __restrict__ e_i, const float* __restrict__ e_j,
                   float* __restrict__ h, float* __restrict__ s_i, float* __restrict__ s_j){
  __shared__ float lw[FIN*DIM]; // lw[f*64+d]
  int t = threadIdx.x;
  for (int u = t; u < FIN*DIM; u += 256){
    int d = u >> 4, f = u & 15;
    lw[f*DIM + d] = lin_w[u];
  }
  __syncthreads();
  int wave = t >> 6, lane = t & 63;
  int r = blockIdx.x*4 + wave;
  int n = r & (NN-1);
  float dval = (lane < FIN) ? data[r*FIN + lane] : 0.f;
  float acc = 0.f;
  #pragma unroll
  for (int f = 0; f < FIN; f++){
    float dv = __shfl(dval, f, 64);
    acc += dv * lw[f*DIM + lane];
  }
  h[r*DIM + lane] = acc;
  float si = wred_sum(acc * att_i[lane]);
  float sj = wred_sum(acc * att_j[lane]);
  if (lane == 0){ s_i[r] = si + e_i[n]; s_j[r] = sj + e_j[n]; }
}

// ------- kD: softmax over K + gather aggregation + BN1 stats -------------
__global__ void kD(const float* __restrict__ h, const float* __restrict__ s_i,
                   const float* __restrict__ s_j, const int* __restrict__ topk,
                   const float* __restrict__ gnn_bias,
                   float* __restrict__ outp, float* __restrict__ acc){
  __shared__ float chs[DIM], chq[DIM];
  int t = threadIdx.x, wave = t >> 6, lane = t & 63;
  if (t < DIM){ chs[t] = 0.f; chq[t] = 0.f; }
  __syncthreads();
  float gb = gnn_bias[lane];
  float psum = 0.f, psq = 0.f;
  int r0 = blockIdx.x*32 + wave*8;
  for (int i = 0; i < 8; i++){
    int r = r0 + i;
    int b = r >> 10, n = r & (NN-1);
    int idx = 0; float tv = -1e30f;
    if (lane < KK){
      idx = topk[n*KK + lane];
      float x = s_i[r] + s_j[b*NN + idx];
      tv = (x > 0.f) ? x : SLOPE * x;
    }
    float m = wred_max(tv);
    float e = (lane < KK) ? expf(tv - m) : 0.f;
    float s = wred_sum(e);
    float a = e / s;
    const float* hb = h + (size_t)b * NN * DIM;
    float o = 0.f;
    #pragma unroll
    for (int k = 0; k < KK; k++){
      float av = __shfl(a, k, 64);
      int   jv = __shfl(idx, k, 64);
      o += av * hb[jv*DIM + lane];
    }
    o += gb;
    outp[(size_t)r*DIM + lane] = o;
    psum += o; psq += o*o;
  }
  atomicAdd(&chs[lane], psum);
  atomicAdd(&chq[lane], psq);
  __syncthreads();
  if (t < DIM){ atomicAdd(&acc[t], chs[t]); atomicAdd(&acc[64+t], chq[t]); }
}

// ---------------- kE: BN finalize -> scale/bias --------------------------
__global__ void kE(const float* __restrict__ acc, const float* __restrict__ gamma,
                   const float* __restrict__ beta, float* __restrict__ prm){
  int d = threadIdx.x;
  float mean = acc[d]    * (1.f / BN_COUNT);
  float var  = acc[64+d] * (1.f / BN_COUNT) - mean*mean;
  float sc = gamma[d] * rsqrtf(var + EPSV);
  prm[d]    = sc;
  prm[64+d] = beta[d] - mean*sc;
}

// ------- kF: BN1 apply + relu + *emb -> rep ; BN2 stats ------------------
__global__ void kF(const float* __restrict__ outp, const float* __restrict__ emb,
                   const float* __restrict__ prm, float* __restrict__ rep,
                   float* __restrict__ acc2){
  __shared__ float chs[DIM], chq[DIM];
  int t = threadIdx.x;
  if (t < DIM){ chs[t] = 0.f; chq[t] = 0.f; }
  __syncthreads();
  int cbase = (t*4) & 63;
  float4 sc = *(const float4*)(prm + cbase);
  float4 bs = *(const float4*)(prm + 64 + cbase);
  float s0=0,s1=0,s2=0,s3=0,q0=0,q1=0,q2=0,q3=0;
  const float4* op4 = (const float4*)outp;
  const float4* em4 = (const float4*)emb;
  float4* rp4 = (float4*)rep;
  const int total = BB*NN*DIM/4;
  for (int e = blockIdx.x*256 + t; e < total; e += 256*256){
    float4 x = op4[e];
    float4 em = em4[e & (NN*DIM/4 - 1)];
    float4 y;
    y.x = fmaxf(x.x*sc.x + bs.x, 0.f) * em.x;
    y.y = fmaxf(x.y*sc.y + bs.y, 0.f) * em.y;
    y.z = fmaxf(x.z*sc.z + bs.z, 0.f) * em.z;
    y.w = fmaxf(x.w*sc.w + bs.w, 0.f) * em.w;
    rp4[e] = y;
    s0 += y.x; q0 += y.x*y.x;
    s1 += y.y; q1 += y.y*y.y;
    s2 += y.z; q2 += y.z*y.z;
    s3 += y.w; q3 += y.w*y.w;
  }
  atomicAdd(&chs[cbase+0], s0); atomicAdd(&chq[cbase+0], q0);
  atomicAdd(&chs[cbase+1], s1); atomicAdd(&chq[cbase+1], q1);
  atomicAdd(&chs[cbase+2], s2); atomicAdd(&chq[cbase+2], q2);
  atomicAdd(&chs[cbase+3], s3); atomicAdd(&chq[cbase+3], q3);
  __syncthreads();
  if (t < DIM){ atomicAdd(&acc2[t], chs[t]); atomicAdd(&acc2[64+t], chq[t]); }
}

// ------- kH: BN2 apply + relu + dot(out_w) -> fore -----------------------
__global__ void kH(const float* __restrict__ rep, const float* __restrict__ prm2,
                   const float* __restrict__ out_w, const float* __restrict__ out_b,
                   float* __restrict__ out){
  int t = threadIdx.x, wave = t >> 6, lane = t & 63;
  int c16 = lane & 15, rsub = lane >> 4;
  float4 sc = *(const float4*)(prm2 + c16*4);
  float4 bs = *(const float4*)(prm2 + 64 + c16*4);
  float4 w4 = *(const float4*)(out_w + c16*4);
  float ob = out_b[0];
  int rbase = blockIdx.x*64 + wave*16;
  for (int i = 0; i < 16; i += 4){
    int r = rbase + i + rsub;
    float4 x = *(const float4*)(rep + (size_t)r*DIM + c16*4);
    float p = fmaxf(x.x*sc.x + bs.x, 0.f) * w4.x
            + fmaxf(x.y*sc.y + bs.y, 0.f) * w4.y
            + fmaxf(x.z*sc.z + bs.z, 0.f) * w4.z
            + fmaxf(x.w*sc.w + bs.w, 0.f) * w4.w;
    p += __shfl_xor(p, 1, 64); p += __shfl_xor(p, 2, 64);
    p += __shfl_xor(p, 4, 64); p += __shfl_xor(p, 8, 64);
    if (c16 == 0) out[r] = p + ob;
  }
}

extern "C" void kernel_launch(void* const* d_in, const int* in_sizes, int n_in,
                              void* d_out, int out_size, void* d_ws, size_t ws_size,
                              hipStream_t stream) {
  const float* data     = (const float*)d_in[0];
  // d_in[1] org_edge_index: unused by the reference computation
  const float* emb      = (const float*)d_in[2];
  const float* lin_w    = (const float*)d_in[3];
  const float* att_i    = (const float*)d_in[4];
  const float* att_j    = (const float*)d_in[5];
  const float* att_em_i = (const float*)d_in[6];
  const float* att_em_j = (const float*)d_in[7];
  const float* gnn_bias = (const float*)d_in[8];
  const float* bn1_g    = (const float*)d_in[9];
  const float* bn1_b    = (const float*)d_in[10];
  const float* bn2_g    = (const float*)d_in[11];
  const float* bn2_b    = (const float*)d_in[12];
  const float* out_w    = (const float*)d_in[13];
  const float* out_b    = (const float*)d_in[14];
  float* out = (float*)d_out;

  float* ws   = (float*)d_ws;
  float* h    = ws;                        // 4194304 floats (aliased by rep later)
  float* outp = ws + 4194304;              // 4194304
  float* s_i  = ws + 8388608;              // 65536
  float* s_j  = s_i + 65536;               // 65536
  float* e_i  = s_j + 65536;               // 1024
  float* e_j  = e_i + NN;                  // 1024
  float* nrmv = e_j + NN;                  // 1024
  int*   topk = (int*)(nrmv + NN);         // 20480 ints
  float* acc  = (float*)(topk + NN*KK);    // 256 floats (bn1 sum/sq, bn2 sum/sq)
  float* prm  = acc + 256;                 // 256 floats (bn1 sc/bias, bn2 sc/bias)
  float* rep  = h;                         // alias: h is dead after kD

  hipMemsetAsync(acc, 0, 256*sizeof(float), stream);
  kA<<<NN, 64, 0, stream>>>(emb, att_em_i, att_em_j, nrmv, e_i, e_j);
  kB<<<NN, 256, 0, stream>>>(emb, nrmv, topk);
  kC<<<(BB*NN)/4, 256, 0, stream>>>(data, lin_w, att_i, att_j, e_i, e_j, h, s_i, s_j);
  kD<<<(BB*NN)/32, 256, 0, stream>>>(h, s_i, s_j, topk, gnn_bias, outp, acc);
  kE<<<1, 64, 0, stream>>>(acc, bn1_g, bn1_b, prm);
  kF<<<256, 256, 0, stream>>>(outp, emb, prm, rep, acc + 128);
  kE<<<1, 64, 0, stream>>>(acc + 128, bn2_g, bn2_b, prm + 128);
  kH<<<NN, 256, 0, stream>>>(rep, prm + 128, out_w, out_b, out);
}

// Round 2
// 263.315 us; speedup vs baseline: 1.0601x; 1.0601x over previous
//
#include <hip/hip_runtime.h>
#include <math.h>

#define BB   64
#define NN   1024
#define FIN  16
#define DIM  64
#define KK   20
#define EPSV 1e-5f
#define SLOPE 0.2f
#define BN_COUNT (BB*NN)

__device__ inline float wred_sum(float v){
  #pragma unroll
  for (int m = 32; m > 0; m >>= 1) v += __shfl_xor(v, m, 64);
  return v;
}
__device__ inline float wred_max(float v){
  #pragma unroll
  for (int m = 32; m > 0; m >>= 1) v = fmaxf(v, __shfl_xor(v, m, 64));
  return v;
}

// ---------------- kA: norms + emb·att_em_i / emb·att_em_j ----------------
__global__ void kA(const float* __restrict__ emb,
                   const float* __restrict__ att_em_i,
                   const float* __restrict__ att_em_j,
                   float* __restrict__ nrm, float* __restrict__ e_i, float* __restrict__ e_j){
  int n = blockIdx.x, d = threadIdx.x;
  float v = emb[n*DIM + d];
  float ss = wred_sum(v*v);
  float di = wred_sum(v*att_em_i[d]);
  float dj = wred_sum(v*att_em_j[d]);
  if (d == 0){ nrm[n] = sqrtf(ss); e_i[n] = di; e_j[n] = dj; }
}

// ---------------- kB: per-row cosine + top-20 (lax.top_k semantics) ------
// 256 threads compute the 1024 cosines; then wave 0 alone does 20 rounds of
// shfl-butterfly argmax (no __syncthreads in the selection loop).
__global__ void kB(const float* __restrict__ emb, const float* __restrict__ nrm,
                   int* __restrict__ topk){
  __shared__ float cosv[NN];
  __shared__ __align__(16) float embi[DIM];
  int i = blockIdx.x, t = threadIdx.x;
  if (t < DIM) embi[t] = emb[i*DIM + t];
  __syncthreads();
  float ni = nrm[i];
  int g = t >> 4, l16 = t & 15;
  const float4* e4 = (const float4*)emb;
  float4 a4 = ((const float4*)embi)[l16];
  for (int jb = 0; jb < NN; jb += 16){
    int j = jb + g;
    float4 b4 = e4[j*(DIM/4) + l16];
    float p = a4.x*b4.x + a4.y*b4.y + a4.z*b4.z + a4.w*b4.w;
    p += __shfl_xor(p, 1, 64); p += __shfl_xor(p, 2, 64);
    p += __shfl_xor(p, 4, 64); p += __shfl_xor(p, 8, 64);
    if (l16 == 0) cosv[j] = p / (ni * nrm[j]);
  }
  __syncthreads();
  if (t < 64){
    int lane = t;
    #pragma unroll 1
    for (int k = 0; k < KK; k++){
      // local scan of 16 entries; strict > keeps lowest j on ties
      float bestv = -1e30f; int bestj = NN;
      int jb = lane*16;
      #pragma unroll
      for (int m = 0; m < 16; m++){
        float v = cosv[jb + m];
        if (v > bestv){ bestv = v; bestj = jb + m; }
      }
      // butterfly argmax across 64 lanes, ties -> lower index
      #pragma unroll
      for (int msk = 32; msk > 0; msk >>= 1){
        float pv = __shfl_xor(bestv, msk, 64);
        int   pj = __shfl_xor(bestj, msk, 64);
        if (pv > bestv || (pv == bestv && pj < bestj)){ bestv = pv; bestj = pj; }
      }
      if (lane == 0) topk[i*KK + k] = bestj;
      if ((bestj >> 4) == lane) cosv[bestj] = -1e30f;  // kill for next round
    }
  }
}

// ---------------- kC: h = data @ lin_w^T ; s_i, s_j ----------------------
__global__ void kC(const float* __restrict__ data, const float* __restrict__ lin_w,
                   const float* __restrict__ att_i, const float* __restrict__ att_j,
                   const float* __restrict__ e_i, const float* __restrict__ e_j,
                   float* __restrict__ h, float* __restrict__ s_i, float* __restrict__ s_j){
  __shared__ float lw[FIN*DIM]; // lw[f*64+d]
  int t = threadIdx.x;
  for (int u = t; u < FIN*DIM; u += 256){
    int d = u >> 4, f = u & 15;
    lw[f*DIM + d] = lin_w[u];
  }
  __syncthreads();
  int wave = t >> 6, lane = t & 63;
  int r = blockIdx.x*4 + wave;
  int n = r & (NN-1);
  float dval = (lane < FIN) ? data[r*FIN + lane] : 0.f;
  float acc = 0.f;
  #pragma unroll
  for (int f = 0; f < FIN; f++){
    float dv = __shfl(dval, f, 64);
    acc += dv * lw[f*DIM + lane];
  }
  h[r*DIM + lane] = acc;
  float si = wred_sum(acc * att_i[lane]);
  float sj = wred_sum(acc * att_j[lane]);
  if (lane == 0){ s_i[r] = si + e_i[n]; s_j[r] = sj + e_j[n]; }
}

// ------- kD: softmax over K + gather aggregation + BN1 stats -------------
// Block->row mapping is XCD-swizzled: heuristic xcd = blockIdx % 8; each XCD
// handles only batches b with b%8==xcd, so its L2 working set of h is
// 8 slabs * 256 KB = 2 MB < 4 MB per-XCD L2.
__global__ void kD(const float* __restrict__ h, const float* __restrict__ s_i,
                   const float* __restrict__ s_j, const int* __restrict__ topk,
                   const float* __restrict__ gnn_bias,
                   float* __restrict__ outp, float* __restrict__ acc){
  __shared__ float chs[DIM], chq[DIM];
  int t = threadIdx.x, wave = t >> 6, lane = t & 63;
  if (t < DIM){ chs[t] = 0.f; chq[t] = 0.f; }
  __syncthreads();
  int p = blockIdx.x;
  int xcd = p & 7, slot = p >> 3;
  int b = xcd + 8*(slot >> 5);     // 8 batches per XCD
  int chunk = slot & 31;           // 32 row-chunks per batch
  float gb = gnn_bias[lane];
  float psum = 0.f, psq = 0.f;
  int n0 = chunk*32 + wave*8;
  const float* hb = h + (size_t)b * NN * DIM;
  for (int i = 0; i < 8; i++){
    int n = n0 + i;
    int r = b*NN + n;
    int idx = 0; float tv = -1e30f;
    if (lane < KK){
      idx = topk[n*KK + lane];
      float x = s_i[r] + s_j[b*NN + idx];
      tv = (x > 0.f) ? x : SLOPE * x;
    }
    float m = wred_max(tv);
    float e = (lane < KK) ? expf(tv - m) : 0.f;
    float s = wred_sum(e);
    float a = e / s;
    float o = 0.f;
    #pragma unroll
    for (int k = 0; k < KK; k++){
      float av = __shfl(a, k, 64);
      int   jv = __shfl(idx, k, 64);
      o += av * hb[jv*DIM + lane];
    }
    o += gb;
    outp[(size_t)r*DIM + lane] = o;
    psum += o; psq += o*o;
  }
  atomicAdd(&chs[lane], psum);
  atomicAdd(&chq[lane], psq);
  __syncthreads();
  if (t < DIM){ atomicAdd(&acc[t], chs[t]); atomicAdd(&acc[64+t], chq[t]); }
}

// ---------------- kE: BN finalize -> scale/bias --------------------------
__global__ void kE(const float* __restrict__ acc, const float* __restrict__ gamma,
                   const float* __restrict__ beta, float* __restrict__ prm){
  int d = threadIdx.x;
  float mean = acc[d]    * (1.f / BN_COUNT);
  float var  = acc[64+d] * (1.f / BN_COUNT) - mean*mean;
  float sc = gamma[d] * rsqrtf(var + EPSV);
  prm[d]    = sc;
  prm[64+d] = beta[d] - mean*sc;
}

// ------- kF: BN1 apply + relu + *emb -> rep ; BN2 stats ------------------
__global__ void kF(const float* __restrict__ outp, const float* __restrict__ emb,
                   const float* __restrict__ prm, float* __restrict__ rep,
                   float* __restrict__ acc2){
  __shared__ float chs[DIM], chq[DIM];
  int t = threadIdx.x;
  if (t < DIM){ chs[t] = 0.f; chq[t] = 0.f; }
  __syncthreads();
  int cbase = (t*4) & 63;
  float4 sc = *(const float4*)(prm + cbase);
  float4 bs = *(const float4*)(prm + 64 + cbase);
  float s0=0,s1=0,s2=0,s3=0,q0=0,q1=0,q2=0,q3=0;
  const float4* op4 = (const float4*)outp;
  const float4* em4 = (const float4*)emb;
  float4* rp4 = (float4*)rep;
  const int total = BB*NN*DIM/4;
  for (int e = blockIdx.x*256 + t; e < total; e += 256*256){
    float4 x = op4[e];
    float4 em = em4[e & (NN*DIM/4 - 1)];
    float4 y;
    y.x = fmaxf(x.x*sc.x + bs.x, 0.f) * em.x;
    y.y = fmaxf(x.y*sc.y + bs.y, 0.f) * em.y;
    y.z = fmaxf(x.z*sc.z + bs.z, 0.f) * em.z;
    y.w = fmaxf(x.w*sc.w + bs.w, 0.f) * em.w;
    rp4[e] = y;
    s0 += y.x; q0 += y.x*y.x;
    s1 += y.y; q1 += y.y*y.y;
    s2 += y.z; q2 += y.z*y.z;
    s3 += y.w; q3 += y.w*y.w;
  }
  atomicAdd(&chs[cbase+0], s0); atomicAdd(&chq[cbase+0], q0);
  atomicAdd(&chs[cbase+1], s1); atomicAdd(&chq[cbase+1], q1);
  atomicAdd(&chs[cbase+2], s2); atomicAdd(&chq[cbase+2], q2);
  atomicAdd(&chs[cbase+3], s3); atomicAdd(&chq[cbase+3], q3);
  __syncthreads();
  if (t < DIM){ atomicAdd(&acc2[t], chs[t]); atomicAdd(&acc2[64+t], chq[t]); }
}

// ------- kH: BN2 apply + relu + dot(out_w) -> fore -----------------------
__global__ void kH(const float* __restrict__ rep, const float* __restrict__ prm2,
                   const float* __restrict__ out_w, const float* __restrict__ out_b,
                   float* __restrict__ out){
  int t = threadIdx.x, wave = t >> 6, lane = t & 63;
  int c16 = lane & 15, rsub = lane >> 4;
  float4 sc = *(const float4*)(prm2 + c16*4);
  float4 bs = *(const float4*)(prm2 + 64 + c16*4);
  float4 w4 = *(const float4*)(out_w + c16*4);
  float ob = out_b[0];
  int rbase = blockIdx.x*64 + wave*16;
  for (int i = 0; i < 16; i += 4){
    int r = rbase + i + rsub;
    float4 x = *(const float4*)(rep + (size_t)r*DIM + c16*4);
    float p = fmaxf(x.x*sc.x + bs.x, 0.f) * w4.x
            + fmaxf(x.y*sc.y + bs.y, 0.f) * w4.y
            + fmaxf(x.z*sc.z + bs.z, 0.f) * w4.z
            + fmaxf(x.w*sc.w + bs.w, 0.f) * w4.w;
    p += __shfl_xor(p, 1, 64); p += __shfl_xor(p, 2, 64);
    p += __shfl_xor(p, 4, 64); p += __shfl_xor(p, 8, 64);
    if (c16 == 0) out[r] = p + ob;
  }
}

extern "C" void kernel_launch(void* const* d_in, const int* in_sizes, int n_in,
                              void* d_out, int out_size, void* d_ws, size_t ws_size,
                              hipStream_t stream) {
  const float* data     = (const float*)d_in[0];
  // d_in[1] org_edge_index: unused by the reference computation
  const float* emb      = (const float*)d_in[2];
  const float* lin_w    = (const float*)d_in[3];
  const float* att_i    = (const float*)d_in[4];
  const float* att_j    = (const float*)d_in[5];
  const float* att_em_i = (const float*)d_in[6];
  const float* att_em_j = (const float*)d_in[7];
  const float* gnn_bias = (const float*)d_in[8];
  const float* bn1_g    = (const float*)d_in[9];
  const float* bn1_b    = (const float*)d_in[10];
  const float* bn2_g    = (const float*)d_in[11];
  const float* bn2_b    = (const float*)d_in[12];
  const float* out_w    = (const float*)d_in[13];
  const float* out_b    = (const float*)d_in[14];
  float* out = (float*)d_out;

  float* ws   = (float*)d_ws;
  float* h    = ws;                        // 4194304 floats (aliased by rep later)
  float* outp = ws + 4194304;              // 4194304
  float* s_i  = ws + 8388608;              // 65536
  float* s_j  = s_i + 65536;               // 65536
  float* e_i  = s_j + 65536;               // 1024
  float* e_j  = e_i + NN;                  // 1024
  float* nrmv = e_j + NN;                  // 1024
  int*   topk = (int*)(nrmv + NN);         // 20480 ints
  float* acc  = (float*)(topk + NN*KK);    // 256 floats (bn1 sum/sq, bn2 sum/sq)
  float* prm  = acc + 256;                 // 256 floats (bn1 sc/bias, bn2 sc/bias)
  float* rep  = h;                         // alias: h is dead after kD

  hipMemsetAsync(acc, 0, 256*sizeof(float), stream);
  kA<<<NN, 64, 0, stream>>>(emb, att_em_i, att_em_j, nrmv, e_i, e_j);
  kB<<<NN, 256, 0, stream>>>(emb, nrmv, topk);
  kC<<<(BB*NN)/4, 256, 0, stream>>>(data, lin_w, att_i, att_j, e_i, e_j, h, s_i, s_j);
  kD<<<(BB*NN)/32, 256, 0, stream>>>(h, s_i, s_j, topk, gnn_bias, outp, acc);
  kE<<<1, 64, 0, stream>>>(acc, bn1_g, bn1_b, prm);
  kF<<<256, 256, 0, stream>>>(outp, emb, prm, rep, acc + 128);
  kE<<<1, 64, 0, stream>>>(acc + 128, bn2_g, bn2_b, prm + 128);
  kH<<<NN, 256, 0, stream>>>(rep, prm + 128, out_w, out_b, out);
}